// Round 4
// baseline (3634.903 us; speedup 1.0000x reference)
//
#include <hip/hip_runtime.h>

#define NPADC 40
#define NZ 26
#define NXI 120            // interior nx (seismo width)
#define NZP 106
#define NXP 200
#define NCELL (NZP * NXP)

#define KSTEPS 8
#define HALO (2 * KSTEPS)          // 16
#define TZ 14
#define TX 25
#define ZB 8                       // 7*14=98, last tile tz=8
#define XB 8                       // 200/25 exact
#define NBLOCKS (ZB * XB)          // 64
#define EXT_X (TX + 2 * HALO)      // 57
#define EZMAX (TZ + 2 * HALO)      // 46
#define LDSN (EZMAX * EXT_X)       // 2622
#define NTHREADS 512
#define SLOTS 6                    // ceil(LDSN / NTHREADS)

#define AGENT __HIP_MEMORY_SCOPE_AGENT

__device__ __forceinline__ float aload(float* p) {
    return __hip_atomic_load(p, __ATOMIC_RELAXED, AGENT);
}
__device__ __forceinline__ void astore(float* p, float v) {
    __hip_atomic_store(p, v, __ATOMIC_RELAXED, AGENT);
}

// ---- damp profile, matching _damp_profile in fp32 ----
__device__ __forceinline__ float dprof(int idx, int n) {
#pragma clang fp contract(off)
    float fi = (float)idx;
    float left = 1.0f, right = 1.0f;
    if (idx < NPADC) {
        float a = 0.015f * ((float)NPADC - fi);
        left = expf(-(a * a));
    }
    if (idx >= n - NPADC) {
        float a = 0.015f * (fi - (float)(n - NPADC - 1));
        right = expf(-(a * a));
    }
    return left * right;
}

// ---- one-time setup: coefficients into ws, init state buf0, zero flags ----
__global__ void setup_kernel(const float* __restrict__ vp,
                             const float* __restrict__ vs,
                             const float* __restrict__ den,
                             const float* __restrict__ ivec,
                             const float* __restrict__ temp,
                             float* __restrict__ coeff,
                             float* __restrict__ buf0,
                             unsigned* __restrict__ flags) {
#pragma clang fp contract(off)
    int i = blockIdx.x * blockDim.x + threadIdx.x;
    if (i < NBLOCKS) flags[i] = 0u;
    if (i >= NCELL) return;
    int z = i / NXP;
    int x = i - z * NXP;

    float dtx = ivec[3];

    int zi = z - NPADC; zi = zi < 0 ? 0 : (zi > NZ - 1 ? NZ - 1 : zi);
    int xi = x - NPADC; xi = xi < 0 ? 0 : (xi > NXI - 1 ? NXI - 1 : xi);
    float vpv = vp[zi * NXI + xi];
    float vsv = vs[zi * NXI + xi];
    float d = den[i];

    float cav = (vpv * vpv) * d;     // ca
    float cmv = (vsv * vsv) * d;     // cm
    coeff[0 * NCELL + i] = dtx / d;                        // b
    coeff[1 * NCELL + i] = dprof(z, NZP) * dprof(x, NXP);  // damp
    coeff[2 * NCELL + i] = cav;                            // ca
    coeff[3 * NCELL + i] = cav - 2.0f * cmv;               // cl
    coeff[4 * NCELL + i] = dtx * cmv;                      // dtx*cm

    for (int f = 0; f < 5; ++f)
        buf0[f * NCELL + i] = temp[f * NCELL + i];
}

// lds field order: 0=vx 1=vz 2=txx 3=tzz 4=txz ; coeffs live in registers
__global__ __launch_bounds__(NTHREADS)
void persist_kernel(const float* __restrict__ coeff,
                    float* __restrict__ buf0, float* __restrict__ buf1,
                    const float* __restrict__ ivec, const float* __restrict__ s,
                    const int* __restrict__ iszp, const int* __restrict__ isxp,
                    float* __restrict__ fields_out,
                    float* __restrict__ illum_out,
                    float* __restrict__ seismo,
                    unsigned* __restrict__ flags,
                    int nt) {
#pragma clang fp contract(off)
    __shared__ float lds[5][LDSN];
    __shared__ float lill[TZ * TX];

    const int tid = threadIdx.x;
    const int bid = blockIdx.x;
    const int zb = bid / XB, xb = bid - zb * XB;
    const int z0 = zb * TZ, x0 = xb * TX;
    const int tzb = (NZP - z0 < TZ) ? (NZP - z0) : TZ;   // 14 or 8
    const int ez = tzb + 2 * HALO;                        // 46 or 40
    const int ncells = ez * EXT_X;
    const float dt  = ivec[2];
    const float dtx = ivec[3];
    const int isz = *iszp, isx = *isxp;

    // ---- per-thread slot precompute (coords, wrap, ownership, coeffs) ----
    int rcA[SLOTS], gA[SLOTS], izA[SLOTS], ixA[SLOTS], seisA[SLOTS], lilA[SLOTS];
    float cb[SLOTS], cd[SLOTS], cca[SLOTS], ccl[SLOTS], cdtcm[SLOTS];
    for (int k = 0; k < SLOTS; ++k) {
        int rc = tid + k * NTHREADS;
        rcA[k] = rc;
        if (rc < ncells) {
            int iz = rc / EXT_X, ix = rc - iz * EXT_X;
            izA[k] = iz; ixA[k] = ix;
            int gz = z0 - HALO + iz; gz += (gz < 0) ? NZP : 0; gz -= (gz >= NZP) ? NZP : 0;
            int gx = x0 - HALO + ix; gx += (gx < 0) ? NXP : 0; gx -= (gx >= NXP) ? NXP : 0;
            int g = gz * NXP + gx;
            gA[k] = g;
            cb[k]    = coeff[0 * NCELL + g];
            cd[k]    = coeff[1 * NCELL + g];
            cca[k]   = coeff[2 * NCELL + g];
            ccl[k]   = coeff[3 * NCELL + g];
            cdtcm[k] = coeff[4 * NCELL + g];
            int liz = iz - HALO, lix = ix - HALO;
            bool inter = (liz >= 0 && liz < tzb && lix >= 0 && lix < TX);
            int gzi = z0 + liz, gxi = x0 + lix;
            seisA[k] = (inter && gzi == NPADC + 1 && gxi >= NPADC && gxi < NPADC + NXI)
                           ? (gxi - NPADC) : -1;
            lilA[k] = inter ? (liz * TX + lix) : -1;
        } else {
            izA[k] = -1000; ixA[k] = -1000; gA[k] = 0; seisA[k] = -1; lilA[k] = -1;
            cb[k] = cd[k] = cca[k] = ccl[k] = cdtcm[k] = 0.0f;
        }
    }
    // source cell local index (injective: ez<=NZP, EXT_X<=NXP)
    int lzs = isz - (z0 - HALO); lzs = ((lzs % NZP) + NZP) % NZP;
    int lxs = isx - (x0 - HALO); lxs = ((lxs % NXP) + NXP) % NXP;
    const int src_rc = (lzs < ez && lxs < EXT_X) ? lzs * EXT_X + lxs : -1;

    // interior store slot (tzb*TX <= 350 < NTHREADS: one slot)
    int st_g = -1, st_e = 0, st_l = 0;
    if (tid < tzb * TX) {
        int liz = tid / TX, lix = tid - liz * TX;
        st_g = (z0 + liz) * NXP + (x0 + lix);
        st_e = (liz + HALO) * EXT_X + (lix + HALO);
        st_l = tid;
    }

    for (int rc = tid; rc < tzb * TX; rc += NTHREADS) lill[rc] = 0.0f;

    // ---- time loop: K-step trapezoid chunks, lightweight grid barrier ----
    int t0 = 0, parity = 0;
    unsigned chunk = 0;
    while (t0 < nt) {
        const int ks = (nt - t0 >= KSTEPS) ? KSTEPS : (nt - t0);
        const bool last = (t0 + ks >= nt);
        float* srcb = parity ? buf1 : buf0;
        float* dstb = last ? fields_out : (parity ? buf0 : buf1);

        // load ext tile (coherent agent-scope loads, no fence needed)
        for (int k = 0; k < SLOTS; ++k) if (rcA[k] < ncells) {
            int rc = rcA[k], g = gA[k];
            lds[0][rc] = aload(&srcb[0 * NCELL + g]);
            lds[1][rc] = aload(&srcb[1 * NCELL + g]);
            lds[2][rc] = aload(&srcb[2 * NCELL + g]);
            lds[3][rc] = aload(&srcb[3 * NCELL + g]);
            lds[4][rc] = aload(&srcb[4 * NCELL + g]);
        }
        __syncthreads();

        for (int p = 1; p <= 2 * ks; ++p) {
            const int t = t0 + ((p + 1) >> 1) - 1;
            const int lo = p, hiZ = ez - p, hiX = EXT_X - p;
            if (p & 1) {
                // velocity phase
                for (int k = 0; k < SLOTS; ++k) {
                    int iz = izA[k], ix = ixA[k];
                    if (iz < lo || iz >= hiZ || ix < lo || ix >= hiX) continue;
                    int rc = rcA[k];
                    float bv = cb[k], dv = cd[k];
                    float t1 = lds[2][rc + 1]     - lds[2][rc];
                    float t2 = lds[4][rc]         - lds[4][rc - EXT_X];
                    float nvx = (lds[0][rc] + bv * (t1 + t2)) * dv;
                    float t3 = lds[3][rc + EXT_X] - lds[3][rc];
                    float t4 = lds[4][rc]         - lds[4][rc - 1];
                    float nvz = (lds[1][rc] + bv * (t3 + t4)) * dv;
                    lds[0][rc] = nvx;
                    lds[1][rc] = nvz;
                    if (seisA[k] >= 0) seismo[t * NXI + seisA[k]] = nvz;
                }
            } else {
                // stress phase
                for (int k = 0; k < SLOTS; ++k) {
                    int iz = izA[k], ix = ixA[k];
                    if (iz < lo || iz >= hiZ || ix < lo || ix >= hiX) continue;
                    int rc = rcA[k];
                    float dv = cd[k];
                    float exx = lds[0][rc] - lds[0][rc - 1];
                    float ezz = lds[1][rc] - lds[1][rc - EXT_X];
                    float e1 = cca[k] * exx;
                    float e2 = ccl[k] * ezz;
                    float ntxx = (lds[2][rc] + dtx * (e1 + e2)) * dv;
                    float e3 = ccl[k] * exx;
                    float e4 = cca[k] * ezz;
                    float ntzz = (lds[3][rc] + dtx * (e3 + e4)) * dv;
                    float p1 = lds[0][rc + EXT_X] - lds[0][rc];
                    float p2 = lds[1][rc + 1]     - lds[1][rc];
                    float ntxz = (lds[4][rc] + cdtcm[k] * (p1 + p2)) * dv;
                    if (rc == src_rc) {
                        float sv = s[t] * dt;
                        ntxx += sv;
                        ntzz += sv;
                    }
                    lds[2][rc] = ntxx;
                    lds[3][rc] = ntzz;
                    lds[4][rc] = ntxz;
                    if (lilA[k] >= 0) {
                        float divv = exx + ezz;
                        lill[lilA[k]] += divv * divv;
                    }
                }
            }
            __syncthreads();
        }

        // store interior (coherent agent-scope stores)
        if (st_g >= 0) {
            astore(&dstb[0 * NCELL + st_g], lds[0][st_e]);
            astore(&dstb[1 * NCELL + st_g], lds[1][st_e]);
            astore(&dstb[2 * NCELL + st_g], lds[2][st_e]);
            astore(&dstb[3 * NCELL + st_g], lds[3][st_e]);
            astore(&dstb[4 * NCELL + st_g], lds[4][st_e]);
            if (last) illum_out[st_g] = lill[st_l];
        }

        t0 += ks; parity ^= 1; ++chunk;

        if (!last) {
            // drain own stores to the coherence point, then publish
            asm volatile("s_waitcnt vmcnt(0)" ::: "memory");
            __syncthreads();
            if (tid == 0)
                __hip_atomic_store(&flags[bid], chunk, __ATOMIC_RELAXED, AGENT);
            // all-to-all: lane tid polls flags[tid]; wave reconverges when all done
            if (tid < NBLOCKS) {
                while (__hip_atomic_load(&flags[tid], __ATOMIC_RELAXED, AGENT) < chunk)
                    __builtin_amdgcn_s_sleep(2);
            }
            __syncthreads();
        }
    }
}

extern "C" void kernel_launch(void* const* d_in, const int* in_sizes, int n_in,
                              void* d_out, int out_size, void* d_ws, size_t ws_size,
                              hipStream_t stream) {
    const float* vp   = (const float*)d_in[0];
    const float* vs   = (const float*)d_in[1];
    const float* den  = (const float*)d_in[2];
    const float* ivec = (const float*)d_in[3];
    const float* temp = (const float*)d_in[4];
    const float* s    = (const float*)d_in[5];
    const int*   isz  = (const int*)d_in[7];
    const int*   isx  = (const int*)d_in[8];
    int nt = in_sizes[5];

    float* out    = (float*)d_out;
    float* fields = out;                        // uu1: 5*NCELL
    float* seismo = out + 5 * NCELL;            // nt*NXI
    float* illum  = seismo + (size_t)nt * NXI;  // NCELL

    float* ws    = (float*)d_ws;
    float* coeff = ws;                 // 5*NCELL
    float* buf0  = ws + 5 * NCELL;     // 5*NCELL
    float* buf1  = ws + 10 * NCELL;    // 5*NCELL
    unsigned* flags = (unsigned*)(ws + 15 * NCELL);   // NBLOCKS

    setup_kernel<<<(NCELL + 255) / 256, 256, 0, stream>>>(
        vp, vs, den, ivec, temp, coeff, buf0, flags);

    persist_kernel<<<NBLOCKS, NTHREADS, 0, stream>>>(
        coeff, buf0, buf1, ivec, s, isz, isx,
        fields, illum, seismo, flags, nt);
}